// Round 1
// baseline (295.475 us; speedup 1.0000x reference)
//
#include <hip/hip_runtime.h>
#include <stdint.h>

#define T_SEQ 2048
#define NB    4
#define NH    16
#define DH    64
#define DM    1024
#define MTOT  (NB * T_SEQ)  // 8192

typedef __attribute__((ext_vector_type(8))) short  short8;
typedef __attribute__((ext_vector_type(8))) __bf16 bf16x8;
typedef __attribute__((ext_vector_type(4))) float  f32x4;
typedef __attribute__((ext_vector_type(4))) unsigned short ushort4v;
typedef unsigned short ushort;

__device__ __forceinline__ ushort f2bf(float x) {
    unsigned int u = __builtin_bit_cast(unsigned int, x);
    u += 0x7FFFu + ((u >> 16) & 1u);          // RNE
    return (ushort)(u >> 16);
}

__device__ __forceinline__ f32x4 mfma_bf16(short8 a, short8 b, f32x4 c) {
    return __builtin_amdgcn_mfma_f32_16x16x32_bf16(
        __builtin_bit_cast(bf16x8, a), __builtin_bit_cast(bf16x8, b), c, 0, 0, 0);
}

#define GLOBAL_AS(p) ((const __attribute__((address_space(1))) void*)(p))
#define LDS_AS(p)    ((__attribute__((address_space(3))) void*)(p))

// ---------------------------------------------------------------- weight cvt
__global__ void cvt_kernel(const float* __restrict__ src, ushort* __restrict__ dst, int n4) {
    int i = blockIdx.x * 256 + threadIdx.x;
    if (i >= n4) return;
    f32x4 v = ((const f32x4*)src)[i];
    ushort4v r;
    r[0] = f2bf(v[0]); r[1] = f2bf(v[1]); r[2] = f2bf(v[2]); r[3] = f2bf(v[3]);
    ((ushort4v*)dst)[i] = r;
}

// ---------------------------------------------------------------- GEMM
// C(M x 1024) = X @ W^T + bias.  W stored row-major [n][k] (bf16 in ws).
// MODE 0: X is f32 (reg-staged, converted), out scattered bf16 [b][h][t][d], scaled.
// MODE 1: X is bf16 ws (global_load_lds), out plain f32 row-major (d_out).
template <int MODE>
__global__ __launch_bounds__(256, 2)
void gemm_kernel(const void* __restrict__ Xv, const ushort* __restrict__ Wb,
                 const float* __restrict__ bias, void* __restrict__ outv, float scale)
{
    __shared__ __align__(16) ushort sA[128 * 64];
    __shared__ __align__(16) ushort sB[128 * 64];

    const int tid  = threadIdx.x;
    const int lane = tid & 63;
    const int w    = tid >> 6;
    const int wr   = (w >> 1) * 64;
    const int wc   = (w & 1) * 64;
    const int bm   = (blockIdx.x & 63) * 128;   // 64 M-tiles
    const int bn   = (blockIdx.x >> 6) * 128;   // 8  N-tiles
    const int lr   = lane & 15;
    const int lk   = lane >> 4;

    f32x4 acc[4][4] = {};

    for (int kt = 0; kt < DM; kt += 64) {
        __syncthreads();
        // ---- stage A tile (rows bm..bm+127, cols kt..kt+63)
        if constexpr (MODE == 0) {
            const float* X = (const float*)Xv;
            #pragma unroll
            for (int i = 0; i < 4; ++i) {
                int ofs  = i * 4096 + w * 1024 + lane * 16;  // bf16-byte offset
                int row  = ofs >> 7;
                int colB = ofs & 127;
                const float* src = X + (size_t)(bm + row) * DM + kt + (colB >> 1);
                f32x4 v0 = *(const f32x4*)(src);
                f32x4 v1 = *(const f32x4*)(src + 4);
                short8 pk;
                pk[0] = (short)f2bf(v0[0]); pk[1] = (short)f2bf(v0[1]);
                pk[2] = (short)f2bf(v0[2]); pk[3] = (short)f2bf(v0[3]);
                pk[4] = (short)f2bf(v1[0]); pk[5] = (short)f2bf(v1[1]);
                pk[6] = (short)f2bf(v1[2]); pk[7] = (short)f2bf(v1[3]);
                *(short8*)((char*)sA + row * 128 + (colB ^ ((row & 7) << 4))) = pk;
            }
        } else {
            const ushort* X = (const ushort*)Xv;
            #pragma unroll
            for (int i = 0; i < 4; ++i) {
                int ofs  = i * 4096 + w * 1024 + lane * 16;
                int row  = ofs >> 7;
                int colB = (ofs & 127) ^ ((row & 7) << 4);
                const char* src = (const char*)X + ((size_t)(bm + row) * DM + kt) * 2 + colB;
                char* dst = (char*)sA + i * 4096 + w * 1024;
                __builtin_amdgcn_global_load_lds(GLOBAL_AS(src), LDS_AS(dst), 16, 0, 0);
            }
        }
        // ---- stage B tile (W rows bn..bn+127, cols kt..kt+63) via global_load_lds
        #pragma unroll
        for (int i = 0; i < 4; ++i) {
            int ofs  = i * 4096 + w * 1024 + lane * 16;
            int row  = ofs >> 7;
            int colB = (ofs & 127) ^ ((row & 7) << 4);
            const char* src = (const char*)Wb + ((size_t)(bn + row) * DM + kt) * 2 + colB;
            char* dst = (char*)sB + i * 4096 + w * 1024;
            __builtin_amdgcn_global_load_lds(GLOBAL_AS(src), LDS_AS(dst), 16, 0, 0);
        }
        __syncthreads();

        // ---- compute
        #pragma unroll
        for (int kk = 0; kk < 2; ++kk) {
            short8 af[4], bfr[4];
            #pragma unroll
            for (int m = 0; m < 4; ++m) {
                int row = wr + m * 16 + lr;
                int cB  = (kk * 64 + lk * 16) ^ ((row & 7) << 4);
                af[m] = *(const short8*)((const char*)sA + row * 128 + cB);
            }
            #pragma unroll
            for (int n = 0; n < 4; ++n) {
                int row = wc + n * 16 + lr;
                int cB  = (kk * 64 + lk * 16) ^ ((row & 7) << 4);
                bfr[n] = *(const short8*)((const char*)sB + row * 128 + cB);
            }
            #pragma unroll
            for (int m = 0; m < 4; ++m)
                #pragma unroll
                for (int n = 0; n < 4; ++n)
                    acc[m][n] = mfma_bf16(af[m], bfr[n], acc[m][n]);
        }
    }

    // ---- epilogue
    #pragma unroll
    for (int m = 0; m < 4; ++m) {
        #pragma unroll
        for (int n = 0; n < 4; ++n) {
            int col   = bn + wc + n * 16 + lr;
            float bv  = bias[col];
            #pragma unroll
            for (int j = 0; j < 4; ++j) {
                int row   = bm + wr + m * 16 + lk * 4 + j;
                float val = (acc[m][n][j] + bv) * scale;
                if constexpr (MODE == 0) {
                    int b = row >> 11, t = row & (T_SEQ - 1);
                    int h = col >> 6,  d = col & 63;
                    ((ushort*)outv)[((size_t)((b * NH + h) * T_SEQ + t)) * DH + d] = f2bf(val);
                } else {
                    ((float*)outv)[(size_t)row * DM + col] = val;
                }
            }
        }
    }
}

// ---------------------------------------------------------------- attention
// One block per (b*H+h, 64-row q-tile). 4 waves; wave w owns q rows [q0, q0+16).
__global__ __launch_bounds__(256, 2)
void attn_kernel(const ushort* __restrict__ Q, const ushort* __restrict__ K,
                 const ushort* __restrict__ V, ushort* __restrict__ O)
{
    __shared__ __align__(16) ushort sK[64 * 64];       // [kpos][d], swizzled
    __shared__ __align__(16) ushort sV[64 * 64];       // transposed [d][kpos], swizzled
    __shared__ __align__(16) ushort sP[4 * 16 * 64];   // per-wave P scratch

    const int tid  = threadIdx.x;
    const int lane = tid & 63;
    const int w    = tid >> 6;
    const int lr   = lane & 15;
    const int lk   = lane >> 4;
    const int bh   = blockIdx.x & 63;
    const int qt   = blockIdx.x >> 6;
    const int b    = bh >> 4, h = bh & 15;

    const ushort* Qbh = Q + (size_t)bh * T_SEQ * DH;
    const ushort* Kbh = K + (size_t)bh * T_SEQ * DH;
    const ushort* Vbh = V + (size_t)bh * T_SEQ * DH;

    const int q0 = qt * 64 + w * 16;

    short8 qf[2];
    #pragma unroll
    for (int kk = 0; kk < 2; ++kk)
        qf[kk] = *(const short8*)(Qbh + (size_t)(q0 + lr) * DH + kk * 32 + lk * 8);

    float mrow[4] = {-1e30f, -1e30f, -1e30f, -1e30f};
    float lsum[4] = {0.f, 0.f, 0.f, 0.f};
    f32x4 o4[4]   = {};
    ushort* sPw   = sP + w * 1024;

    for (int kv = 0; kv <= qt; ++kv) {
        __syncthreads();
        // stage K tile [64][64] via global_load_lds, pre-swizzled source
        #pragma unroll
        for (int i = 0; i < 2; ++i) {
            int ofs  = i * 4096 + w * 1024 + lane * 16;
            int row  = ofs >> 7;
            int colB = (ofs & 127) ^ ((row & 7) << 4);
            const char* src = (const char*)Kbh + (size_t)(kv * 64 + row) * 128 + colB;
            char* dst = (char*)sK + i * 4096 + w * 1024;
            __builtin_amdgcn_global_load_lds(GLOBAL_AS(src), LDS_AS(dst), 16, 0, 0);
        }
        // stage V transposed: thread reads V[kpos][d0..d0+8), writes sV[d][kpos]
        {
            int kp = tid >> 3;
            int d0 = (tid & 7) * 8;
            #pragma unroll
            for (int hlf = 0; hlf < 2; ++hlf) {
                int kpos = kp + hlf * 32;
                short8 vv = *(const short8*)(Vbh + (size_t)(kv * 64 + kpos) * DH + d0);
                #pragma unroll
                for (int j = 0; j < 8; ++j) {
                    int d    = d0 + j;
                    int addr = d * 128 + ((kpos * 2) ^ ((d & 7) << 4));
                    *(ushort*)((char*)sV + addr) = (ushort)vv[j];
                }
            }
        }
        __syncthreads();

        // S = Q K^T   (S[q][kpos]; q in C-rows, kpos in C-cols)
        f32x4 s[4] = {};
        #pragma unroll
        for (int kk = 0; kk < 2; ++kk) {
            #pragma unroll
            for (int c = 0; c < 4; ++c) {
                int row = c * 16 + lr;
                int cB  = (kk * 64 + lk * 16) ^ ((row & 7) << 4);
                short8 kf = *(const short8*)((const char*)sK + row * 128 + cB);
                s[c] = mfma_bf16(qf[kk], kf, s[c]);
            }
        }
        if (kv == qt) {   // causal mask, diagonal tile only
            #pragma unroll
            for (int c = 0; c < 4; ++c)
                #pragma unroll
                for (int j = 0; j < 4; ++j)
                    if (c * 16 + lr > w * 16 + lk * 4 + j) s[c][j] = -1e30f;
        }
        // online softmax (row stats live in the 16 lanes sharing lk)
        float alpha[4];
        #pragma unroll
        for (int j = 0; j < 4; ++j) {
            float tm = fmaxf(fmaxf(s[0][j], s[1][j]), fmaxf(s[2][j], s[3][j]));
            tm = fmaxf(tm, __shfl_xor(tm, 1));
            tm = fmaxf(tm, __shfl_xor(tm, 2));
            tm = fmaxf(tm, __shfl_xor(tm, 4));
            tm = fmaxf(tm, __shfl_xor(tm, 8));
            float mn = fmaxf(mrow[j], tm);
            alpha[j] = __expf(mrow[j] - mn);
            mrow[j]  = mn;
        }
        float rs[4] = {0.f, 0.f, 0.f, 0.f};
        #pragma unroll
        for (int c = 0; c < 4; ++c) {
            #pragma unroll
            for (int j = 0; j < 4; ++j) {
                float pv = __expf(s[c][j] - mrow[j]);
                rs[j] += pv;
                int prow = lk * 4 + j;
                int pcB  = ((c * 16 + lr) * 2) ^ ((prow & 7) << 4);
                *(ushort*)((char*)sPw + prow * 128 + pcB) = f2bf(pv);
            }
        }
        #pragma unroll
        for (int j = 0; j < 4; ++j) {
            rs[j] += __shfl_xor(rs[j], 1);
            rs[j] += __shfl_xor(rs[j], 2);
            rs[j] += __shfl_xor(rs[j], 4);
            rs[j] += __shfl_xor(rs[j], 8);
            lsum[j] = lsum[j] * alpha[j] + rs[j];
        }
        #pragma unroll
        for (int c = 0; c < 4; ++c)
            #pragma unroll
            for (int j = 0; j < 4; ++j)
                o4[c][j] *= alpha[j];

        // O += P V   (A = P from sPw, B = V^T rows from sV)
        #pragma unroll
        for (int kk = 0; kk < 2; ++kk) {
            int pcB = (kk * 64 + lk * 16) ^ ((lr & 7) << 4);
            short8 pa = *(const short8*)((const char*)sPw + lr * 128 + pcB);
            #pragma unroll
            for (int c = 0; c < 4; ++c) {
                int row = c * 16 + lr;
                int cB  = (kk * 64 + lk * 16) ^ ((row & 7) << 4);
                short8 vf = *(const short8*)((const char*)sV + row * 128 + cB);
                o4[c] = mfma_bf16(pa, vf, o4[c]);
            }
        }
    }

    // epilogue: write [b][t][h*64+d] bf16 into attn-out ws
    #pragma unroll
    for (int c = 0; c < 4; ++c) {
        #pragma unroll
        for (int j = 0; j < 4; ++j) {
            int t = q0 + lk * 4 + j;
            int d = c * 16 + lr;
            float val = o4[c][j] / lsum[j];
            O[(size_t)(b * T_SEQ + t) * DM + h * DH + d] = f2bf(val);
        }
    }
}

// ---------------------------------------------------------------- launch
extern "C" void kernel_launch(void* const* d_in, const int* in_sizes, int n_in,
                              void* d_out, int out_size, void* d_ws, size_t ws_size,
                              hipStream_t stream)
{
    const float* query = (const float*)d_in[0];
    const float* key_t = (const float*)d_in[1];
    const float* value = (const float*)d_in[2];
    const float* Wq = (const float*)d_in[3];
    const float* bq = (const float*)d_in[4];
    const float* Wk = (const float*)d_in[5];
    const float* bk = (const float*)d_in[6];
    const float* Wv = (const float*)d_in[7];
    const float* bv = (const float*)d_in[8];
    const float* Wo = (const float*)d_in[9];
    const float* bo = (const float*)d_in[10];
    float* out = (float*)d_out;

    char* ws = (char*)d_ws;
    const size_t WSZ = (size_t)DM * DM * 2;          // 2 MB per weight
    const size_t PSZ = (size_t)MTOT * DM * 2;        // 16 MB per projection
    ushort* Wq_b = (ushort*)(ws);
    ushort* Wk_b = (ushort*)(ws + WSZ);
    ushort* Wv_b = (ushort*)(ws + 2 * WSZ);
    ushort* Wo_b = (ushort*)(ws + 3 * WSZ);
    ushort* Qp   = (ushort*)(ws + 4 * WSZ);
    ushort* Kp   = (ushort*)(ws + 4 * WSZ + PSZ);
    ushort* Vp   = (ushort*)(ws + 4 * WSZ + 2 * PSZ);
    ushort* AO   = (ushort*)(ws + 4 * WSZ + 3 * PSZ);

    const int n4 = DM * DM / 4;          // 262144 float4 per weight
    cvt_kernel<<<n4 / 256, 256, 0, stream>>>(Wq, Wq_b, n4);
    cvt_kernel<<<n4 / 256, 256, 0, stream>>>(Wk, Wk_b, n4);
    cvt_kernel<<<n4 / 256, 256, 0, stream>>>(Wv, Wv_b, n4);
    cvt_kernel<<<n4 / 256, 256, 0, stream>>>(Wo, Wo_b, n4);

    // projections: fold softmax 1/sqrt(64) into Q
    gemm_kernel<0><<<512, 256, 0, stream>>>(query, Wq_b, bq, Qp, 0.125f);
    gemm_kernel<0><<<512, 256, 0, stream>>>(key_t, Wk_b, bk, Kp, 1.0f);
    gemm_kernel<0><<<512, 256, 0, stream>>>(value, Wv_b, bv, Vp, 1.0f);

    attn_kernel<<<64 * 32, 256, 0, stream>>>(Qp, Kp, Vp, AO);

    gemm_kernel<1><<<512, 256, 0, stream>>>(AO, Wo_b, bo, out, 1.0f);
}

// Round 2
// 207.187 us; speedup vs baseline: 1.4261x; 1.4261x over previous
//
#include <hip/hip_runtime.h>
#include <stdint.h>

#define T_SEQ 2048
#define NB    4
#define NH    16
#define DH    64
#define DM    1024
#define MTOT  (NB * T_SEQ)  // 8192

typedef __attribute__((ext_vector_type(8))) short  short8;
typedef __attribute__((ext_vector_type(8))) __bf16 bf16x8;
typedef __attribute__((ext_vector_type(4))) float  f32x4;
typedef __attribute__((ext_vector_type(4))) unsigned short ushort4v;
typedef unsigned short ushort;
typedef unsigned long long u64;

__device__ __forceinline__ ushort f2bf(float x) {
    unsigned int u = __builtin_bit_cast(unsigned int, x);
    u += 0x7FFFu + ((u >> 16) & 1u);          // RNE
    return (ushort)(u >> 16);
}

__device__ __forceinline__ f32x4 mfma_bf16(short8 a, short8 b, f32x4 c) {
    return __builtin_amdgcn_mfma_f32_16x16x32_bf16(
        __builtin_bit_cast(bf16x8, a), __builtin_bit_cast(bf16x8, b), c, 0, 0, 0);
}

#define GLOBAL_AS(p) ((const __attribute__((address_space(1))) void*)(p))
#define LDS_AS(p)    ((__attribute__((address_space(3))) void*)(p))

// ---------------------------------------------------------------- weight cvt
// All 4 weights converted in one launch; dst regions are contiguous in ws.
__global__ void cvt4_kernel(const float* __restrict__ s0, const float* __restrict__ s1,
                            const float* __restrict__ s2, const float* __restrict__ s3,
                            ushort* __restrict__ dst) {
    int i = blockIdx.x * 256 + threadIdx.x;        // 0 .. 4*262144-1 (float4 units)
    int which = i >> 18;                           // 262144 float4 per weight
    int loc   = i & 262143;
    const float* s = which == 0 ? s0 : which == 1 ? s1 : which == 2 ? s2 : s3;
    f32x4 v = ((const f32x4*)s)[loc];
    ushort4v r;
    r[0] = f2bf(v[0]); r[1] = f2bf(v[1]); r[2] = f2bf(v[2]); r[3] = f2bf(v[3]);
    ((ushort4v*)dst)[i] = r;
}

// ---------------------------------------------------------------- GEMM
// C(M x 1024) = X @ W^T + bias.  W stored row-major [n][k] (bf16 in ws).
// MODE 0: X f32 (reg-staged cvt), out scattered bf16 [b][h][t][d], scaled.
// MODE 1: X bf16 ws (global_load_lds), out f32 row-major (d_out).
// MODE 2: X f32, out transposed bf16 [b][h][d][t] (V^T for attention).
template <int MODE>
__global__ __launch_bounds__(256, 2)
void gemm_kernel(const void* __restrict__ Xv, const ushort* __restrict__ Wb,
                 const float* __restrict__ bias, void* __restrict__ outv, float scale)
{
    __shared__ __align__(16) ushort sA[128 * 64];
    __shared__ __align__(16) ushort sB[128 * 64];

    const int tid  = threadIdx.x;
    const int lane = tid & 63;
    const int w    = tid >> 6;
    const int wr   = (w >> 1) * 64;
    const int wc   = (w & 1) * 64;
    const int bm   = (blockIdx.x & 63) * 128;   // 64 M-tiles
    const int bn   = (blockIdx.x >> 6) * 128;   // 8  N-tiles
    const int lr   = lane & 15;
    const int lk   = lane >> 4;

    f32x4 acc[4][4] = {};

    for (int kt = 0; kt < DM; kt += 64) {
        __syncthreads();
        // ---- stage A tile (rows bm..bm+127, cols kt..kt+63)
        if constexpr (MODE == 0 || MODE == 2) {
            const float* X = (const float*)Xv;
            #pragma unroll
            for (int i = 0; i < 4; ++i) {
                int ofs  = i * 4096 + w * 1024 + lane * 16;  // bf16-byte offset
                int row  = ofs >> 7;
                int colB = ofs & 127;
                const float* src = X + (size_t)(bm + row) * DM + kt + (colB >> 1);
                f32x4 v0 = *(const f32x4*)(src);
                f32x4 v1 = *(const f32x4*)(src + 4);
                short8 pk;
                pk[0] = (short)f2bf(v0[0]); pk[1] = (short)f2bf(v0[1]);
                pk[2] = (short)f2bf(v0[2]); pk[3] = (short)f2bf(v0[3]);
                pk[4] = (short)f2bf(v1[0]); pk[5] = (short)f2bf(v1[1]);
                pk[6] = (short)f2bf(v1[2]); pk[7] = (short)f2bf(v1[3]);
                *(short8*)((char*)sA + row * 128 + (colB ^ ((row & 7) << 4))) = pk;
            }
        } else {
            const ushort* X = (const ushort*)Xv;
            #pragma unroll
            for (int i = 0; i < 4; ++i) {
                int ofs  = i * 4096 + w * 1024 + lane * 16;
                int row  = ofs >> 7;
                int colB = (ofs & 127) ^ ((row & 7) << 4);
                const char* src = (const char*)X + ((size_t)(bm + row) * DM + kt) * 2 + colB;
                char* dst = (char*)sA + i * 4096 + w * 1024;
                __builtin_amdgcn_global_load_lds(GLOBAL_AS(src), LDS_AS(dst), 16, 0, 0);
            }
        }
        // ---- stage B tile (W rows bn..bn+127, cols kt..kt+63) via global_load_lds
        #pragma unroll
        for (int i = 0; i < 4; ++i) {
            int ofs  = i * 4096 + w * 1024 + lane * 16;
            int row  = ofs >> 7;
            int colB = (ofs & 127) ^ ((row & 7) << 4);
            const char* src = (const char*)Wb + ((size_t)(bn + row) * DM + kt) * 2 + colB;
            char* dst = (char*)sB + i * 4096 + w * 1024;
            __builtin_amdgcn_global_load_lds(GLOBAL_AS(src), LDS_AS(dst), 16, 0, 0);
        }
        __syncthreads();

        // ---- compute
        #pragma unroll
        for (int kk = 0; kk < 2; ++kk) {
            short8 af[4], bfr[4];
            #pragma unroll
            for (int m = 0; m < 4; ++m) {
                int row = wr + m * 16 + lr;
                int cB  = (kk * 64 + lk * 16) ^ ((row & 7) << 4);
                af[m] = *(const short8*)((const char*)sA + row * 128 + cB);
            }
            #pragma unroll
            for (int n = 0; n < 4; ++n) {
                int row = wc + n * 16 + lr;
                int cB  = (kk * 64 + lk * 16) ^ ((row & 7) << 4);
                bfr[n] = *(const short8*)((const char*)sB + row * 128 + cB);
            }
            #pragma unroll
            for (int m = 0; m < 4; ++m)
                #pragma unroll
                for (int n = 0; n < 4; ++n)
                    acc[m][n] = mfma_bf16(af[m], bfr[n], acc[m][n]);
        }
    }

    // ---- epilogue
    #pragma unroll
    for (int m = 0; m < 4; ++m) {
        #pragma unroll
        for (int n = 0; n < 4; ++n) {
            int col   = bn + wc + n * 16 + lr;
            float bv  = bias[col];
            if constexpr (MODE == 2) {
                // pack 4 consecutive-t bf16 into one u64, store to V^T [bh][d][t]
                int row0 = bm + wr + m * 16 + lk * 4;
                int b = row0 >> 11, t0 = row0 & (T_SEQ - 1);
                int h = col >> 6,  d = col & 63;
                u64 pk = 0;
                #pragma unroll
                for (int j = 0; j < 4; ++j)
                    pk |= (u64)f2bf(acc[m][n][j] + bv) << (16 * j);
                *(u64*)((ushort*)outv + ((size_t)((b * NH + h) * DH + d)) * T_SEQ + t0) = pk;
            } else {
                #pragma unroll
                for (int j = 0; j < 4; ++j) {
                    int row   = bm + wr + m * 16 + lk * 4 + j;
                    float val = (acc[m][n][j] + bv) * scale;
                    if constexpr (MODE == 0) {
                        int b = row >> 11, t = row & (T_SEQ - 1);
                        int h = col >> 6,  d = col & 63;
                        ((ushort*)outv)[((size_t)((b * NH + h) * T_SEQ + t)) * DH + d] = f2bf(val);
                    } else {
                        ((float*)outv)[(size_t)row * DM + col] = val;
                    }
                }
            }
        }
    }
}

// ---------------------------------------------------------------- attention
// One block per (b*H+h, 64-row q-tile). 4 waves; wave w owns q rows [q0, q0+16).
// K staged [kpos][d]; V pre-transposed in gmem, staged [d][kpos]. Double-buffered.
__global__ __launch_bounds__(256, 4)
void attn_kernel(const ushort* __restrict__ Q, const ushort* __restrict__ K,
                 const ushort* __restrict__ Vt, ushort* __restrict__ O)
{
    __shared__ __align__(16) ushort sK[2][64 * 64];
    __shared__ __align__(16) ushort sV[2][64 * 64];
    __shared__ __align__(16) ushort sP[4 * 16 * 64];

    const int tid  = threadIdx.x;
    const int lane = tid & 63;
    const int w    = tid >> 6;
    const int lr   = lane & 15;
    const int lk   = lane >> 4;
    const int bh   = blockIdx.x & 63;
    const int qt   = 31 - (blockIdx.x >> 6);     // long tiles first
    const int b    = bh >> 4, h = bh & 15;

    const ushort* Qbh = Q  + (size_t)bh * T_SEQ * DH;
    const ushort* Kbh = K  + (size_t)bh * T_SEQ * DH;
    const ushort* Vbh = Vt + (size_t)bh * DH * T_SEQ;   // [d][t]

    const int q0 = qt * 64 + w * 16;

    // staging coords (wave-linear LDS dst, pre-swizzled global src)
    const int srow = (lane >> 3);                 // +i*32 + w*8
    const int scol = (lane & 7) * 16;

    auto STAGE = [&](int kv, int buf) {
        #pragma unroll
        for (int i = 0; i < 2; ++i) {
            int row  = i * 32 + w * 8 + srow;
            int colB = scol ^ ((row & 7) << 4);
            __builtin_amdgcn_global_load_lds(
                GLOBAL_AS((const char*)Kbh + (size_t)(kv * 64 + row) * 128 + colB),
                LDS_AS((char*)&sK[buf][0] + i * 4096 + w * 1024 + lane * 16), 16, 0, 0);
        }
        #pragma unroll
        for (int i = 0; i < 2; ++i) {
            int row  = i * 32 + w * 8 + srow;     // d
            int colB = scol ^ ((row & 7) << 4);
            __builtin_amdgcn_global_load_lds(
                GLOBAL_AS((const char*)Vbh + (size_t)row * (T_SEQ * 2) + (size_t)kv * 128 + colB),
                LDS_AS((char*)&sV[buf][0] + i * 4096 + w * 1024 + lane * 16), 16, 0, 0);
        }
    };

    short8 qf[2];
    #pragma unroll
    for (int kk = 0; kk < 2; ++kk)
        qf[kk] = *(const short8*)(Qbh + (size_t)(q0 + lr) * DH + kk * 32 + lk * 8);

    float mrow[4] = {-1e30f, -1e30f, -1e30f, -1e30f};
    float lsum[4] = {0.f, 0.f, 0.f, 0.f};        // per-lane partial (reduced at end)
    f32x4 o4[4]   = {};
    ushort* sPw   = sP + w * 1024;

    STAGE(0, 0);

    for (int kv = 0; kv <= qt; ++kv) {
        const int cur = kv & 1;
        __syncthreads();                          // implicit vmcnt(0): stage(kv) done
        if (kv < qt) STAGE(kv + 1, cur ^ 1);

        // S = Q K^T
        f32x4 s[4] = {};
        __builtin_amdgcn_s_setprio(1);
        #pragma unroll
        for (int kk = 0; kk < 2; ++kk) {
            #pragma unroll
            for (int c = 0; c < 4; ++c) {
                int row = c * 16 + lr;
                int cB  = (kk * 64 + lk * 16) ^ ((row & 7) << 4);
                short8 kf = *(const short8*)((const char*)&sK[cur][0] + row * 128 + cB);
                s[c] = mfma_bf16(qf[kk], kf, s[c]);
            }
        }
        __builtin_amdgcn_s_setprio(0);

        if (kv == qt) {   // causal mask, diagonal tile only
            #pragma unroll
            for (int c = 0; c < 4; ++c)
                #pragma unroll
                for (int j = 0; j < 4; ++j)
                    if (c * 16 + lr > w * 16 + lk * 4 + j) s[c][j] = -1e30f;
        }
        // online softmax: wave-reduce max over the 16 lr-lanes; lsum kept per-lane
        float alpha[4];
        #pragma unroll
        for (int j = 0; j < 4; ++j) {
            float tm = fmaxf(fmaxf(s[0][j], s[1][j]), fmaxf(s[2][j], s[3][j]));
            tm = fmaxf(tm, __shfl_xor(tm, 1));
            tm = fmaxf(tm, __shfl_xor(tm, 2));
            tm = fmaxf(tm, __shfl_xor(tm, 4));
            tm = fmaxf(tm, __shfl_xor(tm, 8));
            float mn = fmaxf(mrow[j], tm);
            alpha[j] = __expf(mrow[j] - mn);
            mrow[j]  = mn;
        }
        float rs[4] = {0.f, 0.f, 0.f, 0.f};
        #pragma unroll
        for (int c = 0; c < 4; ++c) {
            #pragma unroll
            for (int j = 0; j < 4; ++j) {
                float pv = __expf(s[c][j] - mrow[j]);
                rs[j] += pv;
                int prow = lk * 4 + j;
                int pcB  = ((c * 16 + lr) * 2) ^ ((prow & 7) << 4);
                *(ushort*)((char*)sPw + prow * 128 + pcB) = f2bf(pv);
            }
        }
        #pragma unroll
        for (int j = 0; j < 4; ++j)
            lsum[j] = lsum[j] * alpha[j] + rs[j];
        #pragma unroll
        for (int c = 0; c < 4; ++c)
            #pragma unroll
            for (int j = 0; j < 4; ++j)
                o4[c][j] *= alpha[j];

        // O += P V
        __builtin_amdgcn_s_setprio(1);
        #pragma unroll
        for (int kk = 0; kk < 2; ++kk) {
            int pcB = (kk * 64 + lk * 16) ^ ((lr & 7) << 4);
            short8 pa = *(const short8*)((const char*)sPw + lr * 128 + pcB);
            #pragma unroll
            for (int c = 0; c < 4; ++c) {
                int row = c * 16 + lr;
                int cB  = (kk * 64 + lk * 16) ^ ((row & 7) << 4);
                short8 vf = *(const short8*)((const char*)&sV[cur][0] + row * 128 + cB);
                o4[c] = mfma_bf16(pa, vf, o4[c]);
            }
        }
        __builtin_amdgcn_s_setprio(0);
    }

    // final cross-lane lsum reduction (deferred out of the kv loop)
    #pragma unroll
    for (int j = 0; j < 4; ++j) {
        lsum[j] += __shfl_xor(lsum[j], 1);
        lsum[j] += __shfl_xor(lsum[j], 2);
        lsum[j] += __shfl_xor(lsum[j], 4);
        lsum[j] += __shfl_xor(lsum[j], 8);
    }

    // epilogue: write [b][t][h*64+d] bf16 into attn-out ws
    #pragma unroll
    for (int c = 0; c < 4; ++c) {
        #pragma unroll
        for (int j = 0; j < 4; ++j) {
            int t = q0 + lk * 4 + j;
            int d = c * 16 + lr;
            float val = o4[c][j] / lsum[j];
            O[(size_t)(b * T_SEQ + t) * DM + h * DH + d] = f2bf(val);
        }
    }
}

// ---------------------------------------------------------------- launch
extern "C" void kernel_launch(void* const* d_in, const int* in_sizes, int n_in,
                              void* d_out, int out_size, void* d_ws, size_t ws_size,
                              hipStream_t stream)
{
    const float* query = (const float*)d_in[0];
    const float* key_t = (const float*)d_in[1];
    const float* value = (const float*)d_in[2];
    const float* Wq = (const float*)d_in[3];
    const float* bq = (const float*)d_in[4];
    const float* Wk = (const float*)d_in[5];
    const float* bk = (const float*)d_in[6];
    const float* Wv = (const float*)d_in[7];
    const float* bv = (const float*)d_in[8];
    const float* Wo = (const float*)d_in[9];
    const float* bo = (const float*)d_in[10];
    float* out = (float*)d_out;

    char* ws = (char*)d_ws;
    const size_t WSZ = (size_t)DM * DM * 2;          // 2 MB per weight
    const size_t PSZ = (size_t)MTOT * DM * 2;        // 16 MB per projection
    ushort* Wq_b = (ushort*)(ws);
    ushort* Wk_b = (ushort*)(ws + WSZ);
    ushort* Wv_b = (ushort*)(ws + 2 * WSZ);
    ushort* Wo_b = (ushort*)(ws + 3 * WSZ);
    ushort* Qp   = (ushort*)(ws + 4 * WSZ);
    ushort* Kp   = (ushort*)(ws + 4 * WSZ + PSZ);
    ushort* Vt   = (ushort*)(ws + 4 * WSZ + 2 * PSZ);  // [bh][d][t]
    ushort* AO   = (ushort*)(ws + 4 * WSZ + 3 * PSZ);

    cvt4_kernel<<<4096, 256, 0, stream>>>(Wq, Wk, Wv, Wo, Wq_b);

    // projections: fold softmax 1/sqrt(64) into Q; V written pre-transposed
    gemm_kernel<0><<<512, 256, 0, stream>>>(query, Wq_b, bq, Qp, 0.125f);
    gemm_kernel<0><<<512, 256, 0, stream>>>(key_t, Wk_b, bk, Kp, 1.0f);
    gemm_kernel<2><<<512, 256, 0, stream>>>(value, Wv_b, bv, Vt, 1.0f);

    attn_kernel<<<64 * 32, 256, 0, stream>>>(Qp, Kp, Vt, AO);

    gemm_kernel<1><<<512, 256, 0, stream>>>(AO, Wo_b, bo, out, 1.0f);
}

// Round 3
// 183.220 us; speedup vs baseline: 1.6127x; 1.1308x over previous
//
#include <hip/hip_runtime.h>
#include <stdint.h>

#define T_SEQ 2048
#define NB    4
#define NH    16
#define DH    64
#define DM    1024
#define MTOT  (NB * T_SEQ)  // 8192

typedef __attribute__((ext_vector_type(8)))  short  short8;
typedef __attribute__((ext_vector_type(8)))  __bf16 bf16x8;
typedef __attribute__((ext_vector_type(4)))  float  f32x4;
typedef __attribute__((ext_vector_type(16))) float  f32x16;
typedef __attribute__((ext_vector_type(4)))  unsigned short ushort4v;
typedef __attribute__((ext_vector_type(4)))  unsigned int   uint4v;
typedef unsigned short ushort;
typedef unsigned long long u64;

__device__ __forceinline__ ushort f2bf(float x) {
    unsigned int u = __builtin_bit_cast(unsigned int, x);
    u += 0x7FFFu + ((u >> 16) & 1u);          // RNE
    return (ushort)(u >> 16);
}

__device__ __forceinline__ unsigned cvtpk(float lo, float hi) {
    unsigned r;
    asm("v_cvt_pk_bf16_f32 %0, %1, %2" : "=v"(r) : "v"(lo), "v"(hi));
    return r;
}

__device__ __forceinline__ f32x4 mfma16(short8 a, short8 b, f32x4 c) {
    return __builtin_amdgcn_mfma_f32_16x16x32_bf16(
        __builtin_bit_cast(bf16x8, a), __builtin_bit_cast(bf16x8, b), c, 0, 0, 0);
}
__device__ __forceinline__ f32x16 mfma32(short8 a, short8 b, f32x16 c) {
    return __builtin_amdgcn_mfma_f32_32x32x16_bf16(
        __builtin_bit_cast(bf16x8, a), __builtin_bit_cast(bf16x8, b), c, 0, 0, 0);
}

#define GLOBAL_AS(p) ((const __attribute__((address_space(1))) void*)(p))
#define LDS_AS(p)    ((__attribute__((address_space(3))) void*)(p))

// ---------------------------------------------------------------- weight cvt
__global__ void cvt4_kernel(const float* __restrict__ s0, const float* __restrict__ s1,
                            const float* __restrict__ s2, const float* __restrict__ s3,
                            ushort* __restrict__ dst) {
    int i = blockIdx.x * 256 + threadIdx.x;        // float4 units
    int which = i >> 18;
    int loc   = i & 262143;
    const float* s = which == 0 ? s0 : which == 1 ? s1 : which == 2 ? s2 : s3;
    f32x4 v = ((const f32x4*)s)[loc];
    ushort4v r;
    r[0] = f2bf(v[0]); r[1] = f2bf(v[1]); r[2] = f2bf(v[2]); r[3] = f2bf(v[3]);
    ((ushort4v*)dst)[i] = r;
}

// ---------------------------------------------------------------- GEMM
// C(M x 1024) = X @ W^T + bias.  W row-major [n][k] bf16.
// MODE 0: X f32 (reg-staged cvt), out scattered bf16 [b][h][t][d], scaled.
// MODE 1: X bf16 ws (global_load_lds), out f32 row-major (d_out).
// MODE 2: X f32, out transposed bf16 [b][h][d][t'] with t' = t bits2<->3 swapped.
template <int MODE>
__global__ __launch_bounds__(256, 2)
void gemm_kernel(const void* __restrict__ Xv, const ushort* __restrict__ Wb,
                 const float* __restrict__ bias, void* __restrict__ outv, float scale)
{
    __shared__ __align__(16) ushort sA[128 * 64];
    __shared__ __align__(16) ushort sB[128 * 64];

    const int tid  = threadIdx.x;
    const int lane = tid & 63;
    const int w    = tid >> 6;
    const int wr   = (w >> 1) * 64;
    const int wc   = (w & 1) * 64;
    const int bm   = (blockIdx.x & 63) * 128;
    const int bn   = (blockIdx.x >> 6) * 128;
    const int lr   = lane & 15;
    const int lk   = lane >> 4;

    f32x4 acc[4][4] = {};

    for (int kt = 0; kt < DM; kt += 64) {
        __syncthreads();
        if constexpr (MODE == 0 || MODE == 2) {
            const float* X = (const float*)Xv;
            #pragma unroll
            for (int i = 0; i < 4; ++i) {
                int ofs  = i * 4096 + w * 1024 + lane * 16;
                int row  = ofs >> 7;
                int colB = ofs & 127;
                const float* src = X + (size_t)(bm + row) * DM + kt + (colB >> 1);
                f32x4 v0 = *(const f32x4*)(src);
                f32x4 v1 = *(const f32x4*)(src + 4);
                short8 pk;
                pk[0] = (short)f2bf(v0[0]); pk[1] = (short)f2bf(v0[1]);
                pk[2] = (short)f2bf(v0[2]); pk[3] = (short)f2bf(v0[3]);
                pk[4] = (short)f2bf(v1[0]); pk[5] = (short)f2bf(v1[1]);
                pk[6] = (short)f2bf(v1[2]); pk[7] = (short)f2bf(v1[3]);
                *(short8*)((char*)sA + row * 128 + (colB ^ ((row & 7) << 4))) = pk;
            }
        } else {
            const ushort* X = (const ushort*)Xv;
            #pragma unroll
            for (int i = 0; i < 4; ++i) {
                int ofs  = i * 4096 + w * 1024 + lane * 16;
                int row  = ofs >> 7;
                int colB = (ofs & 127) ^ ((row & 7) << 4);
                const char* src = (const char*)X + ((size_t)(bm + row) * DM + kt) * 2 + colB;
                char* dst = (char*)sA + i * 4096 + w * 1024;
                __builtin_amdgcn_global_load_lds(GLOBAL_AS(src), LDS_AS(dst), 16, 0, 0);
            }
        }
        #pragma unroll
        for (int i = 0; i < 4; ++i) {
            int ofs  = i * 4096 + w * 1024 + lane * 16;
            int row  = ofs >> 7;
            int colB = (ofs & 127) ^ ((row & 7) << 4);
            const char* src = (const char*)Wb + ((size_t)(bn + row) * DM + kt) * 2 + colB;
            char* dst = (char*)sB + i * 4096 + w * 1024;
            __builtin_amdgcn_global_load_lds(GLOBAL_AS(src), LDS_AS(dst), 16, 0, 0);
        }
        __syncthreads();

        #pragma unroll
        for (int kk = 0; kk < 2; ++kk) {
            short8 af[4], bfr[4];
            #pragma unroll
            for (int m = 0; m < 4; ++m) {
                int row = wr + m * 16 + lr;
                int cB  = (kk * 64 + lk * 16) ^ ((row & 7) << 4);
                af[m] = *(const short8*)((const char*)sA + row * 128 + cB);
            }
            #pragma unroll
            for (int n = 0; n < 4; ++n) {
                int row = wc + n * 16 + lr;
                int cB  = (kk * 64 + lk * 16) ^ ((row & 7) << 4);
                bfr[n] = *(const short8*)((const char*)sB + row * 128 + cB);
            }
            #pragma unroll
            for (int m = 0; m < 4; ++m)
                #pragma unroll
                for (int n = 0; n < 4; ++n)
                    acc[m][n] = mfma16(af[m], bfr[n], acc[m][n]);
        }
    }

    #pragma unroll
    for (int m = 0; m < 4; ++m) {
        #pragma unroll
        for (int n = 0; n < 4; ++n) {
            int col   = bn + wc + n * 16 + lr;
            float bv  = bias[col];
            if constexpr (MODE == 2) {
                int row0 = bm + wr + m * 16 + lk * 4;
                int b = row0 >> 11, t0 = row0 & (T_SEQ - 1);
                int h = col >> 6,  d = col & 63;
                int t0p = (t0 & ~12) | ((t0 & 4) << 1) | ((t0 & 8) >> 1);  // swap bits 2,3
                u64 pk = 0;
                #pragma unroll
                for (int j = 0; j < 4; ++j)
                    pk |= (u64)f2bf(acc[m][n][j] + bv) << (16 * j);
                *(u64*)((ushort*)outv + ((size_t)((b * NH + h) * DH + d)) * T_SEQ + t0p) = pk;
            } else {
                #pragma unroll
                for (int j = 0; j < 4; ++j) {
                    int row   = bm + wr + m * 16 + lk * 4 + j;
                    float val = (acc[m][n][j] + bv) * scale;
                    if constexpr (MODE == 0) {
                        int b = row >> 11, t = row & (T_SEQ - 1);
                        int h = col >> 6,  d = col & 63;
                        ((ushort*)outv)[((size_t)((b * NH + h) * T_SEQ + t)) * DH + d] = f2bf(val);
                    } else {
                        ((float*)outv)[(size_t)row * DM + col] = val;
                    }
                }
            }
        }
    }
}

// ---------------------------------------------------------------- attention
// Block = (bh, 128-q-row tile); 4 waves x 32 q-rows. 32x32x16 MFMA, swapped
// QK^T (S^T = K Q^T) so softmax is lane-local; PV uses kpos permuted by
// pi = swap(bit2,bit3) so the P A-fragment is sequential registers (cvt_pk
// only, no cross-lane); V stored pi-permuted in gmem by the V-proj epilogue.
__global__ __launch_bounds__(256)
void attn_kernel(const ushort* __restrict__ Q, const ushort* __restrict__ K,
                 const ushort* __restrict__ Vt, ushort* __restrict__ O)
{
    __shared__ __align__(16) ushort sK[2][64 * 64];
    __shared__ __align__(16) ushort sV[2][64 * 64];

    const int tid  = threadIdx.x;
    const int lane = tid & 63;
    const int w    = tid >> 6;
    const int l31  = lane & 31;
    const int hi   = lane >> 5;
    const int bh   = blockIdx.x & 63;
    const int qt   = 15 - (blockIdx.x >> 6);     // long tiles first
    const int b    = bh >> 4, h = bh & 15;

    const ushort* Qbh = Q + (size_t)bh * T_SEQ * DH;
    const char*   Kc  = (const char*)(K  + (size_t)bh * T_SEQ * DH);
    const char*   Vc  = (const char*)(Vt + (size_t)bh * DH * T_SEQ);

    const int q0w   = qt * 128 + w * 32;
    const int kvmax = 2 * qt + 1;

    const int scolB = (tid & 7) * 16;

    auto STAGE = [&](int kv, int buf) {
        #pragma unroll
        for (int i = 0; i < 2; ++i) {
            int row = i * 32 + (tid >> 3);
            int cB  = scolB ^ ((row & 7) << 4);
            __builtin_amdgcn_global_load_lds(
                GLOBAL_AS(Kc + (size_t)(kv * 64 + row) * 128 + cB),
                LDS_AS((char*)&sK[buf][0] + i * 4096 + tid * 16), 16, 0, 0);
        }
        #pragma unroll
        for (int i = 0; i < 2; ++i) {
            int row = i * 32 + (tid >> 3);       // d
            int cB  = scolB ^ ((row & 7) << 4);
            __builtin_amdgcn_global_load_lds(
                GLOBAL_AS(Vc + (size_t)row * (T_SEQ * 2) + kv * 128 + cB),
                LDS_AS((char*)&sV[buf][0] + i * 4096 + tid * 16), 16, 0, 0);
        }
    };

    // Q fragment: lane holds Q[q0w + l31][dc*16 + hi*8 .. +8)
    short8 qf[4];
    #pragma unroll
    for (int dc = 0; dc < 4; ++dc)
        qf[dc] = *(const short8*)(Qbh + (size_t)(q0w + l31) * DH + dc * 16 + hi * 8);

    f32x16 o0 = {}, o1 = {};
    float mrow = -1e30f, lsum = 0.f;

    STAGE(0, 0);

    for (int kv = 0; kv <= kvmax; ++kv) {
        const int cur = kv & 1;
        __syncthreads();                          // stage(kv) complete
        if (kv < kvmax) STAGE(kv + 1, cur ^ 1);
        if (kv * 64 > q0w + 31) continue;         // wave fully masked this tile

        const char* sk = (const char*)&sK[cur][0];
        const char* sv = (const char*)&sV[cur][0];

        // S^T = K Q^T : s0 = kpos 0..31 (local), s1 = kpos 32..63
        f32x16 s0 = {}, s1 = {};
        __builtin_amdgcn_s_setprio(1);
        #pragma unroll
        for (int dc = 0; dc < 4; ++dc) {
            int cB  = dc * 32 + hi * 16;
            int swz = (l31 & 7) << 4;             // rows l31 and l31+32 share (row&7)
            short8 kf0 = *(const short8*)(sk + l31 * 128 + (cB ^ swz));
            short8 kf1 = *(const short8*)(sk + (32 + l31) * 128 + (cB ^ swz));
            s0 = mfma32(kf0, qf[dc], s0);
            s1 = mfma32(kf1, qf[dc], s1);
        }
        __builtin_amdgcn_s_setprio(0);

        // causal mask (diagonal tiles only); lane's q = q0w + l31
        if (kv * 64 + 63 > q0w) {
            int q = q0w + l31;
            #pragma unroll
            for (int r = 0; r < 16; ++r) {
                int kp = kv * 64 + (r & 3) + 8 * (r >> 2) + 4 * hi;
                if (kp > q)      s0[r] = -1e30f;
                if (kp + 32 > q) s1[r] = -1e30f;
            }
        }

        // row max: in-lane tree + one xor-32 exchange
        float t16[16];
        #pragma unroll
        for (int r = 0; r < 16; ++r) t16[r] = fmaxf(s0[r], s1[r]);
        #pragma unroll
        for (int r = 0; r < 8; ++r)  t16[r] = fmaxf(t16[r], t16[r + 8]);
        #pragma unroll
        for (int r = 0; r < 4; ++r)  t16[r] = fmaxf(t16[r], t16[r + 4]);
        float pm = fmaxf(fmaxf(t16[0], t16[1]), fmaxf(t16[2], t16[3]));
        pm = fmaxf(pm, __shfl_xor(pm, 32));

        // defer-max: rescale only when max grew by > 8 (log2 domain)
        if (__any(pm > mrow + 8.f)) {
            float mn = fmaxf(mrow, pm);
            float al = __builtin_amdgcn_exp2f(mrow - mn);
            mrow = mn;
            lsum *= al;
            #pragma unroll
            for (int r = 0; r < 16; ++r) {
                float aq = __shfl(al, (r & 3) + 8 * (r >> 2) + 4 * hi);
                o0[r] *= aq;
                o1[r] *= aq;
            }
        }

        // P = exp2(S - m)   (log2e folded into Q projection scale)
        float rs = 0.f;
        #pragma unroll
        for (int r = 0; r < 16; ++r) { s0[r] = __builtin_amdgcn_exp2f(s0[r] - mrow); rs += s0[r]; }
        #pragma unroll
        for (int r = 0; r < 16; ++r) { s1[r] = __builtin_amdgcn_exp2f(s1[r] - mrow); rs += s1[r]; }
        lsum += rs;

        // A-fragments: pure in-lane cvt_pk (pi-permuted kpos)
        short8 pa[4];
        #pragma unroll
        for (int seg = 0; seg < 4; ++seg) {
            const f32x16& sp = (seg < 2) ? s0 : s1;
            const int r0 = (seg & 1) * 8;
            uint4v pw;
            pw[0] = cvtpk(sp[r0 + 0], sp[r0 + 1]);
            pw[1] = cvtpk(sp[r0 + 2], sp[r0 + 3]);
            pw[2] = cvtpk(sp[r0 + 4], sp[r0 + 5]);
            pw[3] = cvtpk(sp[r0 + 6], sp[r0 + 7]);
            pa[seg] = __builtin_bit_cast(short8, pw);
        }

        // O += P V  (B rows read pi-ordered from sV, which is pi-stored)
        __builtin_amdgcn_s_setprio(1);
        #pragma unroll
        for (int seg = 0; seg < 4; ++seg) {
            int cB = seg * 32 + hi * 16;
            {
                int d = l31;
                short8 vf = *(const short8*)(sv + d * 128 + (cB ^ ((d & 7) << 4)));
                o0 = mfma32(pa[seg], vf, o0);
            }
            {
                int d = 32 + l31;
                short8 vf = *(const short8*)(sv + d * 128 + (cB ^ ((d & 7) << 4)));
                o1 = mfma32(pa[seg], vf, o1);
            }
        }
        __builtin_amdgcn_s_setprio(0);
    }

    // finish: reduce lsum across the two halves, broadcast 1/lsum per q-reg
    lsum += __shfl_xor(lsum, 32);
    float rl = 1.0f / lsum;
    #pragma unroll
    for (int r = 0; r < 16; ++r) {
        int   ql = (r & 3) + 8 * (r >> 2) + 4 * hi;
        float rq = __shfl(rl, ql);
        int   t  = q0w + ql;
        size_t base = ((size_t)(b * T_SEQ) + t) * DM + h * DH;
        O[base + l31]      = f2bf(o0[r] * rq);
        O[base + 32 + l31] = f2bf(o1[r] * rq);
    }
}

// ---------------------------------------------------------------- launch
extern "C" void kernel_launch(void* const* d_in, const int* in_sizes, int n_in,
                              void* d_out, int out_size, void* d_ws, size_t ws_size,
                              hipStream_t stream)
{
    const float* query = (const float*)d_in[0];
    const float* key_t = (const float*)d_in[1];
    const float* value = (const float*)d_in[2];
    const float* Wq = (const float*)d_in[3];
    const float* bq = (const float*)d_in[4];
    const float* Wk = (const float*)d_in[5];
    const float* bk = (const float*)d_in[6];
    const float* Wv = (const float*)d_in[7];
    const float* bv = (const float*)d_in[8];
    const float* Wo = (const float*)d_in[9];
    const float* bo = (const float*)d_in[10];
    float* out = (float*)d_out;

    char* ws = (char*)d_ws;
    const size_t WSZ = (size_t)DM * DM * 2;
    const size_t PSZ = (size_t)MTOT * DM * 2;
    ushort* Wq_b = (ushort*)(ws);
    ushort* Wk_b = (ushort*)(ws + WSZ);
    ushort* Wv_b = (ushort*)(ws + 2 * WSZ);
    ushort* Wo_b = (ushort*)(ws + 3 * WSZ);
    ushort* Qp   = (ushort*)(ws + 4 * WSZ);
    ushort* Kp   = (ushort*)(ws + 4 * WSZ + PSZ);
    ushort* Vt   = (ushort*)(ws + 4 * WSZ + 2 * PSZ);  // [bh][d][t'] pi-permuted
    ushort* AO   = (ushort*)(ws + 4 * WSZ + 3 * PSZ);

    cvt4_kernel<<<4096, 256, 0, stream>>>(Wq, Wk, Wv, Wo, Wq_b);

    // fold softmax 1/sqrt(64) AND log2(e) into Q scale (exp2-domain softmax)
    gemm_kernel<0><<<512, 256, 0, stream>>>(query, Wq_b, bq, Qp, 0.18033688011112042f);
    gemm_kernel<0><<<512, 256, 0, stream>>>(key_t, Wk_b, bk, Kp, 1.0f);
    gemm_kernel<2><<<512, 256, 0, stream>>>(value, Wv_b, bv, Vt, 1.0f);

    attn_kernel<<<64 * 16, 256, 0, stream>>>(Qp, Kp, Vt, AO);

    gemm_kernel<1><<<512, 256, 0, stream>>>(AO, Wo_b, bo, out, 1.0f);
}